// Round 3
// baseline (276.821 us; speedup 1.0000x reference)
//
#include <hip/hip_runtime.h>
#include <stdint.h>

// GroupedLinear: y[b, g*256+o] = sum_i x[b, g*256+i] * W[g,o,i] + bias[g,o]
// B=8192, G=16. fp32 in/out, bf16 MFMA compute.
// R2 result: traffic at floor (285 MB) but only 2.65 TB/s (42% duty) ->
// latency-bound. R3: async global_load_lds double-buffered A pipeline
// (one barrier/iter, DMA in flight across compute), B direct from L2.

#define IN_F   4096
#define OUT_F  4096
#define GIN    256
#define GOUT   256

#define BM 128
#define BN 128
#define BK 64
#define NK 4            // 256 / BK

using short8  = __attribute__((ext_vector_type(8))) short;
using floatx4 = __attribute__((ext_vector_type(4))) float;

#define GLOBAL_AS __attribute__((address_space(1)))
#define LDS_AS    __attribute__((address_space(3)))

// round-to-nearest-even fp32 -> bf16 (branch-free)
__device__ __forceinline__ short f2bf_rne(float f) {
    unsigned u = __builtin_bit_cast(unsigned, f);
    unsigned r = u + 0x7FFFu + ((u >> 16) & 1u);
    return (short)(r >> 16);
}

__device__ __forceinline__ short8 pack8(floatx4 f0, floatx4 f1) {
    short8 p;
    p[0] = f2bf_rne(f0[0]); p[1] = f2bf_rne(f0[1]);
    p[2] = f2bf_rne(f0[2]); p[3] = f2bf_rne(f0[3]);
    p[4] = f2bf_rne(f1[0]); p[5] = f2bf_rne(f1[1]);
    p[6] = f2bf_rne(f1[2]); p[7] = f2bf_rne(f1[3]);
    return p;
}

__global__ __launch_bounds__(256, 2)
void grouped_linear_kernel(const float* __restrict__ X,
                           const float* __restrict__ W,
                           const float* __restrict__ Bias,
                           float* __restrict__ Out) {
    // A tile staged raw fp32 via async DMA, double-buffered: 2 x 32 KB.
    // Row-major [128][64] fp32 per buffer; 16B granules within each row are
    // XOR-permuted (gdest = gsrc ^ (row&15)) via the *global source* address,
    // since the DMA's LDS side is fixed at base + lane*16.
    __shared__ __align__(16) float lsA[2][BM * BK];

    const int t    = threadIdx.x;
    const int lane = t & 63;
    const int wave = t >> 6;
    const int wm   = wave >> 1;
    const int wn   = wave & 1;
    const int lrow = lane & 15;
    const int quad = lane >> 4;

    const int bn   = blockIdx.x & 31;
    const int bm   = blockIdx.x >> 5;
    const int g    = bn >> 1;
    const int row0 = bm * BM;
    const int col0 = bn * BN;
    const int nlb  = (bn & 1) * BN;

    const float* Wg = W + (size_t)g * GOUT * GIN + (size_t)nlb * GIN;
    const float* Xg = X + (size_t)row0 * IN_F + g * GIN;

    floatx4 acc[4][4];
    #pragma unroll
    for (int i = 0; i < 4; ++i)
        #pragma unroll
        for (int j = 0; j < 4; ++j)
            acc[i][j] = (floatx4){0.f, 0.f, 0.f, 0.f};

    // ---- async stage of tile kt into buffer b (8 DMA insts per wave) ----
    auto stage = [&](int kt, int b) {
        const int kbase = kt * BK;
        #pragma unroll
        for (int i = 0; i < 8; ++i) {
            int ig   = wave * 8 + i;                 // 0..31, wave-uniform
            int row  = ig * 4 + (lane >> 4);         // 0..127
            int gsrc = (lane & 15) ^ (row & 15);     // swizzled source granule
            const float* src = Xg + (size_t)row * IN_F + kbase + gsrc * 4;
            float* dst = &lsA[b][ig * 256];          // 1 KB per inst, uniform base
            __builtin_amdgcn_global_load_lds((const GLOBAL_AS void*)src,
                                             (LDS_AS void*)dst, 16, 0, 0);
        }
    };

    stage(0, 0);
    __syncthreads();   // startup drain (vmcnt(0)) — unavoidable once

    for (int kt = 0; kt < NK; ++kt) {
        const int kbase = kt * BK;

        // ---- B fragment loads, direct from global (L2-hot W). Issued BEFORE
        //      the next DMA so their vmcnt wait doesn't drain the DMA. ----
        floatx4 braw[2][4][2];
        #pragma unroll
        for (int kk = 0; kk < 2; ++kk)
            #pragma unroll
            for (int j = 0; j < 4; ++j) {
                int n = wn * 64 + j * 16 + lrow;
                const float* src = Wg + (size_t)n * GIN + kbase + kk * 32 + quad * 8;
                braw[kk][j][0] = *(const floatx4*)src;
                braw[kk][j][1] = *(const floatx4*)(src + 4);
            }

        // ---- prefetch next A tile (in flight across this whole iteration) ----
        if (kt + 1 < NK) stage(kt + 1, (kt + 1) & 1);

        // ---- cvt B to bf16 frags ----
        short8 bfr[2][4];
        #pragma unroll
        for (int kk = 0; kk < 2; ++kk)
            #pragma unroll
            for (int j = 0; j < 4; ++j)
                bfr[kk][j] = pack8(braw[kk][j][0], braw[kk][j][1]);

        // ---- A frags from LDS (fp32, swizzled) + MFMA ----
        const float* buf = lsA[kt & 1];
        #pragma unroll
        for (int kk = 0; kk < 2; ++kk) {
            short8 a[4];
            #pragma unroll
            for (int i = 0; i < 4; ++i) {
                int row = wm * 64 + i * 16 + lrow;
                int s0  = kk * 8 + quad * 2;         // source granule (8 floats = 2)
                int g0  = s0 ^ (row & 15);
                int g1  = (s0 + 1) ^ (row & 15);
                floatx4 f0 = *(const floatx4*)&buf[row * 64 + g0 * 4];
                floatx4 f1 = *(const floatx4*)&buf[row * 64 + g1 * 4];
                a[i] = pack8(f0, f1);
            }
            #pragma unroll
            for (int i = 0; i < 4; ++i)
                #pragma unroll
                for (int j = 0; j < 4; ++j)
                    acc[i][j] = __builtin_amdgcn_mfma_f32_16x16x32_bf16(
                        a[i], bfr[kk][j], acc[i][j], 0, 0, 0);
        }

        // one barrier per iter: drains the in-flight DMA (vmcnt(0)) AFTER the
        // compute phase has overlapped it, and publishes LDS for all waves.
        if (kt + 1 < NK) __syncthreads();
    }

    // ---- epilogue: C/D layout col=lane&15, row=quad*4+reg; add bias ----
    #pragma unroll
    for (int j = 0; j < 4; ++j) {
        int gc = col0 + wn * 64 + j * 16 + lrow;
        float bias = Bias[gc];
        #pragma unroll
        for (int i = 0; i < 4; ++i) {
            int gr = row0 + wm * 64 + i * 16 + quad * 4;
            floatx4 v = acc[i][j];
            #pragma unroll
            for (int rg = 0; rg < 4; ++rg)
                Out[(size_t)(gr + rg) * OUT_F + gc] = v[rg] + bias;
        }
    }
}

extern "C" void kernel_launch(void* const* d_in, const int* in_sizes, int n_in,
                              void* d_out, int out_size, void* d_ws, size_t ws_size,
                              hipStream_t stream) {
    const float* X    = (const float*)d_in[0];   // [8192, 4096]
    const float* W    = (const float*)d_in[1];   // [16, 256, 256]
    const float* Bias = (const float*)d_in[2];   // [16, 256]
    float*       Out  = (float*)d_out;           // [8192, 4096]

    dim3 grid(64 * 32);
    dim3 block(256);
    grouped_linear_kernel<<<grid, block, 0, stream>>>(X, W, Bias, Out);
}